// Round 2
// baseline (1624.808 us; speedup 1.0000x reference)
//
#include <hip/hip_runtime.h>

#define N_ROWS 65536
#define DIM    1000
#define KCB    256

#define RB     64      // rows per block
#define DT     32      // d-tile
#define PITCH  36      // LDS row pitch (floats)

// ---------- Kernel A: wsq[k] = fl32( sum_d w[k][d]^2 computed in fp64 ) ----------
__global__ __launch_bounds__(256) void wsq_kernel(const float* __restrict__ w,
                                                  float* __restrict__ wsq) {
    const int wave = threadIdx.x >> 6;
    const int lane = threadIdx.x & 63;
    const int k = blockIdx.x * 4 + wave;   // grid 64 blocks x 4 waves = 256
    double s = 0.0;
    for (int c = lane; c < DIM / 4; c += 64) {
        const float4 v = *(const float4*)(w + k * DIM + c * 4);
        s += (double)v.x * v.x + (double)v.y * v.y + (double)v.z * v.z + (double)v.w * v.w;
    }
    #pragma unroll
    for (int off = 32; off; off >>= 1) s += __shfl_down(s, off, 64);
    if (lane == 0) wsq[k] = (float)s;
}

// ---------- Kernel B: xsq[n] = fl32( sum_d x[n][d]^2 computed in fp64 ) ----------
__global__ __launch_bounds__(256) void xsq_kernel(const float* __restrict__ x,
                                                  float* __restrict__ xsq) {
    const int wave = threadIdx.x >> 6;
    const int lane = threadIdx.x & 63;
    const int row = blockIdx.x * 4 + wave; // grid 16384 blocks x 4 waves = 65536
    double s = 0.0;
    for (int c = lane; c < DIM / 4; c += 64) {
        const float4 v = *(const float4*)(x + (size_t)row * DIM + c * 4);
        s += (double)v.x * v.x + (double)v.y * v.y + (double)v.z * v.z + (double)v.w * v.w;
    }
    #pragma unroll
    for (int off = 32; off; off >>= 1) s += __shfl_down(s, off, 64);
    if (lane == 0) xsq[row] = (float)s;
}

// ---------- Kernel C: cross-GEMM (fp64-accurate) + fp32-pipeline argmin + gather ----------
__global__ __launch_bounds__(256) void vq_kernel(const float* __restrict__ x,
                                                 const float* __restrict__ w,
                                                 const float* __restrict__ wsq,
                                                 const float* __restrict__ xsq,
                                                 float* __restrict__ out) {
    __shared__ float Xs[RB * PITCH];
    __shared__ float Ws[KCB * PITCH];
    __shared__ int   lidx[RB];

    const int tid  = threadIdx.x;
    const int row0 = blockIdx.x * RB;

    const int kt = tid & 31;   // k = kt + 32*j
    const int rt = tid >> 5;   // r = rt + 8*i

    double acc[8][8];
    #pragma unroll
    for (int i = 0; i < 8; i++)
        #pragma unroll
        for (int j = 0; j < 8; j++) acc[i][j] = 0.0;

    const int wk = tid >> 3;   // 0..31
    const int wg = tid & 7;    // 0..7
    const int xr = tid >> 2;   // 0..63
    const int xg = tid & 3;    // 0..3

    for (int d0 = 0; d0 < DIM; d0 += DT) {
        #pragma unroll
        for (int p = 0; p < 8; p++) {
            const int k = p * 32 + wk;
            const int d = d0 + wg * 4;
            float4 v = make_float4(0.f, 0.f, 0.f, 0.f);
            if (d < DIM) v = *(const float4*)(w + k * DIM + d);
            *(float4*)(&Ws[k * PITCH + wg * 4]) = v;
        }
        #pragma unroll
        for (int p = 0; p < 2; p++) {
            const int off = (xg + p * 4) * 4;
            const int d = d0 + off;
            float4 v = make_float4(0.f, 0.f, 0.f, 0.f);
            if (d < DIM) v = *(const float4*)(x + (size_t)(row0 + xr) * DIM + d);
            *(float4*)(&Xs[xr * PITCH + off]) = v;
        }
        __syncthreads();

        #pragma unroll
        for (int dq = 0; dq < DT; dq += 4) {
            float4 xf[8], wf[8];
            #pragma unroll
            for (int i = 0; i < 8; i++)
                xf[i] = *(const float4*)(&Xs[(rt + 8 * i) * PITCH + dq]);
            #pragma unroll
            for (int j = 0; j < 8; j++)
                wf[j] = *(const float4*)(&Ws[(kt + 32 * j) * PITCH + dq]);
            #pragma unroll
            for (int i = 0; i < 8; i++)
                #pragma unroll
                for (int j = 0; j < 8; j++) {
                    // fp32 quad-partial (error ~1e-10), flushed exactly into fp64
                    float p = xf[i].x * wf[j].x;
                    p = fmaf(xf[i].y, wf[j].y, p);
                    p = fmaf(xf[i].z, wf[j].z, p);
                    p = fmaf(xf[i].w, wf[j].w, p);
                    acc[i][j] += (double)p;
                }
        }
        __syncthreads();
    }

    // epilogue: replicate np fp32 pipeline: s = fl32( fl32(x_sq - 2*c32) + wsq_k )
    #pragma unroll
    for (int i = 0; i < 8; i++) {
        const float xs = xsq[row0 + rt + 8 * i];
        float bestv = 3.4e38f;
        int   bestk = 0;
        #pragma unroll
        for (int j = 0; j < 8; j++) {
            const int k = kt + 32 * j;
            const float c32 = (float)acc[i][j];       // best fp32 approx of exact cross
            const float t1  = xs - 2.0f * c32;        // fp32 round at ~1000 magnitude
            const float s   = t1 + wsq[k];            // fp32 round again
            if (s < bestv || (s == bestv && k < bestk)) { bestv = s; bestk = k; }
        }
        #pragma unroll
        for (int m = 16; m >= 1; m >>= 1) {
            const float ov = __shfl_xor(bestv, m, 64);
            const int   ok = __shfl_xor(bestk, m, 64);
            if (ov < bestv || (ov == bestv && ok < bestk)) { bestv = ov; bestk = ok; }
        }
        if (kt == 0) lidx[rt + 8 * i] = bestk;
    }
    __syncthreads();

    const int wave = tid >> 6;
    const int lane = tid & 63;
    for (int r = wave; r < RB; r += 4) {
        const int k = lidx[r];
        const float4* src = (const float4*)(w + k * DIM);
        float4* dst = (float4*)(out + (size_t)(row0 + r) * DIM);
        for (int c = lane; c < DIM / 4; c += 64) dst[c] = src[c];
    }
}

extern "C" void kernel_launch(void* const* d_in, const int* in_sizes, int n_in,
                              void* d_out, int out_size, void* d_ws, size_t ws_size,
                              hipStream_t stream) {
    const float* x = (const float*)d_in[0];   // encoder_embedding (N, D)
    const float* w = (const float*)d_in[1];   // weight (K, D)
    float* out = (float*)d_out;
    float* wsq = (float*)d_ws;                // 256 floats
    float* xsq = wsq + KCB;                   // 65536 floats

    wsq_kernel<<<KCB / 4, 256, 0, stream>>>(w, wsq);
    xsq_kernel<<<N_ROWS / 4, 256, 0, stream>>>(x, xsq);
    vq_kernel<<<N_ROWS / RB, 256, 0, stream>>>(x, w, wsq, xsq, out);
}